// Round 12
// baseline (145.602 us; speedup 1.0000x reference)
//
#include <hip/hip_runtime.h>
#include <hip/hip_bf16.h>

#define B_ 4
#define S_ 512
#define E_ 512
#define U_ 256

// 2*log2(e): folded so tanh args feed exp2 directly: exp(2x) = exp2(KC*x)
#define KC 2.885390081777927f

#if __has_builtin(__builtin_amdgcn_exp2f)
#define EXP2F(x) __builtin_amdgcn_exp2f(x)
#else
#define EXP2F(x) __exp2f(x)
#endif
#if __has_builtin(__builtin_amdgcn_rcpf)
#define RCPF(x) __builtin_amdgcn_rcpf(x)
#else
#define RCPF(x) (1.0f / (x))
#endif

typedef __attribute__((ext_vector_type(8))) short bf16x8;
typedef __attribute__((ext_vector_type(4))) float f32x4;

__device__ __forceinline__ unsigned short bf16rn(float x) {
    unsigned int u = __float_as_uint(x);
    u = (u + 0x7FFFu + ((u >> 16) & 1u)) >> 16;   // RNE
    return (unsigned short)u;
}
// truncation split: x = hi + lo (lo exact in fp32); dropped lo*lo term ~2^-16
__device__ __forceinline__ void splitT(float x, short* hi, short* lo) {
    const unsigned u = __float_as_uint(x);
    *hi = (short)(u >> 16);
    const float hf = __uint_as_float(u & 0xFFFF0000u);
    *lo = (short)(__float_as_uint(x - hf) >> 16);
}

// ---------------------------------------------------------------------------
// Kernel 1 (dual role, 1536 blocks x 256 thr) — unchanged from R11.
//  blocks 0..1023 — pre-GEMMs. block <-> (z, ng 0..15 = 16-u slab, mq 0..31).
//      z==0: keySt[b][u][j] = KC*(h1[b,j,:] @ w1[:,u])    (j contiguous)
//      z==1: qryS [b][i][u] = KC*(h2[b,i,:] @ w2[:,u] + b1[u])
//  blocks 1024..1535 — cast h1 -> h1c in MFMA B-frag order (for PV).
// ---------------------------------------------------------------------------
__global__ __launch_bounds__(256) void prep_gemm(
    const float* __restrict__ h1, const float* __restrict__ h2,
    const float* __restrict__ w, const float* __restrict__ b1,
    float* __restrict__ keySt, float* __restrict__ qryS,
    bf16x8* __restrict__ h1c)
{
    __shared__ unsigned short WhiL[16][64][8];   // [kc][lane][j] 16 KB
    __shared__ unsigned short WloL[16][64][8];   // 16 KB

    const int tid = threadIdx.x;
    const int bid = blockIdx.x;

    if (bid < 1024) {
        const int z = bid >> 9, ng = (bid >> 5) & 15, mq = bid & 31;

        // ---- W slab conversion: 16 u-lanes x 16 k-rows per iteration ----
        const int l16c = tid & 15, r16 = tid >> 4;
        const float* __restrict__ Wp = w + (size_t)z * E_ * U_ + ng * 16 + l16c;
#pragma unroll 4
        for (int it = 0; it < 32; ++it) {
            const int k = it * 16 + r16;
            short h, l;
            splitT(Wp[(size_t)k * U_] * KC, &h, &l);
            const int kc = k >> 5, quad = (k >> 3) & 3, jj = k & 7;
            WhiL[kc][quad * 16 + l16c][jj] = (unsigned short)h;
            WloL[kc][quad * 16 + l16c][jj] = (unsigned short)l;
        }
        __syncthreads();

        // ---- MFMA main loop: one 16-row x 16-u tile per wave ----
        const int wv = tid >> 6, lane = tid & 63;
        const int quad = lane >> 4, l16 = lane & 15;
        const int m0 = (mq * 4 + wv) * 16;
        const float* __restrict__ Arow = (z ? h2 : h1) + (size_t)(m0 + l16) * E_;

        f32x4 acc = (f32x4){0.f, 0.f, 0.f, 0.f};

        for (int kc = 0; kc < 16; ++kc) {
            const int kb = kc * 32 + quad * 8;
            const float4 x0 = *(const float4*)&Arow[kb];
            const float4 x1 = *(const float4*)&Arow[kb + 4];
            const float xs[8] = {x0.x, x0.y, x0.z, x0.w, x1.x, x1.y, x1.z, x1.w};
            bf16x8 ah, al;
#pragma unroll
            for (int j = 0; j < 8; ++j) {
                short h, l; splitT(xs[j], &h, &l);
                ah[j] = h; al[j] = l;
            }
            const bf16x8 bh = *(const bf16x8*)&WhiL[kc][lane][0];
            const bf16x8 bl = *(const bf16x8*)&WloL[kc][lane][0];
            acc = __builtin_amdgcn_mfma_f32_16x16x32_bf16(ah, bh, acc, 0, 0, 0);
            acc = __builtin_amdgcn_mfma_f32_16x16x32_bf16(ah, bl, acc, 0, 0, 0);
            acc = __builtin_amdgcn_mfma_f32_16x16x32_bf16(al, bh, acc, 0, 0, 0);
        }

        const int u = ng * 16 + l16;                     // C/D col = u
        if (z == 0) {
            const int b = m0 >> 9;
            const int j0 = (m0 & (S_ - 1)) + quad * 4;   // C/D row = j
            *(float4*)&keySt[((size_t)b * U_ + u) * S_ + j0] =
                make_float4(acc[0], acc[1], acc[2], acc[3]);
        } else {
            const int row = m0 + quad * 4;
            const float bias = KC * b1[u];
#pragma unroll
            for (int r = 0; r < 4; ++r)
                qryS[(size_t)(row + r) * U_ + u] = acc[r] + bias;
        }
    } else {
        // ---- h1 -> bf16 B-frag cast for PV ----
        const int s = (bid - 1024) * 256 + tid;
        const int lane = s & 63, kc = (s >> 6) & 15, et = (s >> 10) & 31, b = s >> 15;
        const int quad = lane >> 4, l16 = lane & 15;
        const float* __restrict__ src =
            h1 + ((size_t)b * S_ + kc * 32 + quad * 8) * E_ + et * 16 + l16;
        bf16x8 c;
#pragma unroll
        for (int j = 0; j < 8; ++j)
            c[j] = (short)bf16rn(src[(size_t)j * E_]);
        h1c[s] = c;
    }
}

// ---------------------------------------------------------------------------
// Kernel 2: scores + softmax + PV, fused (eliminates the pv dispatch and the
// P global roundtrip — residual tracked dispatch COUNT across R7-R11, not
// aux kernel internals).
// TI=8: 512 thr/block, thread t <-> column j = t, EIGHT query rows per
// block. grid (64, 4) = 256 blocks = 1/CU, 8 waves/CU. 8 independent
// accumulator chains per thread; k-loads amortized over 8 rows.
// a = sum_u v_u/(exp2(arg)+1); score = c - 2a (c, b2 cancel) ->
// p ~ exp2(-a*KC); |a*KC| <= ~52 so no max-shift needed.
// Phase 2: P rows -> LDS (16x520 bf16, 8 rows zero), 16x16x32 MFMA vs
// pre-converted h1c B-frags (half-filled A-tile = 2x MFMA waste, ~2us).
// ---------------------------------------------------------------------------
__device__ __forceinline__ float quadTerm(float a0, float a1, float a2, float a3,
                                          float4 vq, float acc) {
    const float F1 = EXP2F(a0) + 1.f;
    const float F2 = EXP2F(a1) + 1.f;
    const float F3 = EXP2F(a2) + 1.f;
    const float F4 = EXP2F(a3) + 1.f;
    const float P12 = F1 * F2, P34 = F3 * F4;
    const float n12 = fmaf(vq.y, F1, vq.x * F2);
    const float n34 = fmaf(vq.w, F3, vq.z * F4);
    const float num = fmaf(n34, P12, n12 * P34);
    return fmaf(num, RCPF(P12 * P34), acc);
}

#define PLD 520   // LDS row stride (bf16): 520*2B -> frag reads 2-way (free)

__global__ __launch_bounds__(512) void scores_pv(
    const float* __restrict__ keySt, const float* __restrict__ qryS,
    const float* __restrict__ v, const bf16x8* __restrict__ h1c,
    float* __restrict__ out)
{
    const int i0 = blockIdx.x * 8;
    const int b = blockIdx.y;
    const int t = threadIdx.x;          // j = t
    const int wv = t >> 6;

    __shared__ unsigned short Pl[16][PLD];   // A-tile staging (16.25 KB)
    __shared__ float ssm[8][8];

    // ---- phase 1: 8 tanh-dot rows ----
    const float4* __restrict__ qv =
        (const float4*)(qryS + ((size_t)b * S_ + i0) * U_);   // row r at +r*64
    const float4* __restrict__ vv4 = (const float4*)v;
    const float* __restrict__ kp = keySt + (size_t)b * U_ * S_ + t;

    float a[8];
#pragma unroll
    for (int r = 0; r < 8; ++r) a[r] = 0.f;

#pragma unroll 2
    for (int ub = 0; ub < U_ / 4; ++ub) {
        const float k0 = kp[(size_t)(ub * 4 + 0) * S_];
        const float k1 = kp[(size_t)(ub * 4 + 1) * S_];
        const float k2 = kp[(size_t)(ub * 4 + 2) * S_];
        const float k3 = kp[(size_t)(ub * 4 + 3) * S_];
        const float4 vq = vv4[ub];                       // uniform -> SGPR
#pragma unroll
        for (int r = 0; r < 8; ++r) {
            const float4 q = qv[r * 64 + ub];            // uniform -> SGPR
            a[r] = quadTerm(q.x + k0, q.y + k1, q.z + k2, q.w + k3, vq, a[r]);
        }
    }

    // ---- softmax over j per row ----
    float p[8], s[8];
#pragma unroll
    for (int r = 0; r < 8; ++r) {
        p[r] = EXP2F(-a[r] * KC);
        s[r] = p[r];
    }
#pragma unroll
    for (int off = 1; off < 64; off <<= 1)
#pragma unroll
        for (int r = 0; r < 8; ++r) s[r] += __shfl_xor(s[r], off, 64);
    if ((t & 63) == 0)
#pragma unroll
        for (int r = 0; r < 8; ++r) ssm[wv][r] = s[r];
    __syncthreads();
#pragma unroll
    for (int r = 0; r < 8; ++r) {
        float acc = ssm[0][r];
#pragma unroll
        for (int k = 1; k < 8; ++k) acc += ssm[k][r];
        s[r] = RCPF(acc);
    }

    // ---- stage P into LDS A-tile ([m][k] rows; unused half zeroed) ----
    const int io = i0 & 15;             // 0 or 8: which half of the 16-tile
#pragma unroll
    for (int r = 0; r < 8; ++r) {
        Pl[io + r][t] = bf16rn(p[r] * s[r]);
        Pl[(io ^ 8) + r][t] = 0;
    }
    __syncthreads();

    // ---- phase 2: PV via MFMA. wave wv -> e-tiles wv*4..+3 ----
    const int lane = t & 63;
    const int quad = lane >> 4, l16 = lane & 15;
    const int itile = i0 >> 4;
    const int row16 = quad * 4;         // C/D rows row16..row16+3
    const bool live = (row16 & 8) == io; // this quad holds real rows

#pragma unroll
    for (int e = 0; e < 4; ++e) {
        const int et = wv * 4 + e;
        const bf16x8* __restrict__ Bb = h1c + ((b * 32 + et) * 16) * 64 + lane;
        f32x4 acc = (f32x4){0.f, 0.f, 0.f, 0.f};
#pragma unroll
        for (int kc = 0; kc < 16; ++kc) {
            const bf16x8 a8 = *(const bf16x8*)&Pl[l16][kc * 32 + quad * 8];
            acc = __builtin_amdgcn_mfma_f32_16x16x32_bf16(a8, Bb[kc * 64], acc, 0, 0, 0);
        }
        if (live) {
            const int ig = itile * 16 + row16;
            float* __restrict__ ob = out + ((size_t)b * S_ + ig) * E_ + et * 16 + l16;
#pragma unroll
            for (int r = 0; r < 4; ++r)
                ob[(size_t)r * E_] = acc[r];
        }
    }
}

extern "C" void kernel_launch(void* const* d_in, const int* in_sizes, int n_in,
                              void* d_out, int out_size, void* d_ws, size_t ws_size,
                              hipStream_t stream) {
    const float* h1 = (const float*)d_in[0];
    const float* h2 = (const float*)d_in[1];
    const float* w  = (const float*)d_in[2];
    const float* b1 = (const float*)d_in[3];
    const float* v  = (const float*)d_in[4];
    // d_in[5] = b2: cancels in softmax, unused.
    float* out = (float*)d_out;

    char* ws = (char*)d_ws;
    float* keySt = (float*)ws;   ws += 2u << 20;  // 2 MB
    float* qryS  = (float*)ws;   ws += 2u << 20;  // 2 MB
    bf16x8* h1c = (bf16x8*)ws;                    // 2 MB

    prep_gemm<<<dim3(1536), dim3(256), 0, stream>>>(h1, h2, w, b1, keySt, qryS, h1c);
    scores_pv<<<dim3(S_ / 8, B_), dim3(512), 0, stream>>>(keySt, qryS, v, h1c, out);
}

// Round 13
// 140.657 us; speedup vs baseline: 1.0352x; 1.0352x over previous
//
#include <hip/hip_runtime.h>
#include <hip/hip_bf16.h>

#define B_ 4
#define S_ 512
#define E_ 512
#define U_ 256

// 2*log2(e): folded so tanh args feed exp2 directly: exp(2x) = exp2(KC*x)
#define KC 2.885390081777927f

#if __has_builtin(__builtin_amdgcn_exp2f)
#define EXP2F(x) __builtin_amdgcn_exp2f(x)
#else
#define EXP2F(x) __exp2f(x)
#endif
#if __has_builtin(__builtin_amdgcn_rcpf)
#define RCPF(x) __builtin_amdgcn_rcpf(x)
#else
#define RCPF(x) (1.0f / (x))
#endif

typedef __attribute__((ext_vector_type(8))) short bf16x8;
typedef __attribute__((ext_vector_type(4))) float f32x4;

__device__ __forceinline__ unsigned short bf16rn(float x) {
    unsigned int u = __float_as_uint(x);
    u = (u + 0x7FFFu + ((u >> 16) & 1u)) >> 16;   // RNE
    return (unsigned short)u;
}
// truncation split: x = hi + lo (lo exact in fp32); dropped lo*lo term ~2^-16
__device__ __forceinline__ void splitT(float x, short* hi, short* lo) {
    const unsigned u = __float_as_uint(x);
    *hi = (short)(u >> 16);
    const float hf = __uint_as_float(u & 0xFFFF0000u);
    *lo = (short)(__float_as_uint(x - hf) >> 16);
}

// ---------------------------------------------------------------------------
// prep (R8 verbatim): one-shot conversions into MFMA B-frag layouts.
//  W slots  (t < 32768):  whi/wlo[((z*16+nt)*16+kc)*64+lane] =
//       split(KC * w[z][kc*32+quad*8+j][nt*16+l16]),  j=0..7
//  h1 slots (t >= 32768): h1c[((b*32+et)*16+kc)*64+lane] =
//       bf16(h1[b][kc*32+quad*8+j][et*16+l16])
// grid 640x256 = 163840 threads, one slot each.
// ---------------------------------------------------------------------------
__global__ __launch_bounds__(256) void prep_kernel(
    const float* __restrict__ w, const float* __restrict__ h1,
    bf16x8* __restrict__ whi, bf16x8* __restrict__ wlo,
    bf16x8* __restrict__ h1c)
{
    const int t = blockIdx.x * 256 + threadIdx.x;
    if (t < 32768) {
        const int lane = t & 63, kc = (t >> 6) & 15, nt = (t >> 10) & 15, z = t >> 14;
        const int quad = lane >> 4, l16 = lane & 15;
        const float* __restrict__ src =
            w + (size_t)z * E_ * U_ + (size_t)(kc * 32 + quad * 8) * U_ + nt * 16 + l16;
        bf16x8 hi, lo;
#pragma unroll
        for (int j = 0; j < 8; ++j) {
            short h, l; splitT(src[(size_t)j * U_] * KC, &h, &l);
            hi[j] = h; lo[j] = l;
        }
        whi[t] = hi; wlo[t] = lo;
    } else {
        const int s = t - 32768;
        const int lane = s & 63, kc = (s >> 6) & 15, et = (s >> 10) & 31, b = s >> 15;
        const int quad = lane >> 4, l16 = lane & 15;
        const float* __restrict__ src =
            h1 + ((size_t)b * S_ + kc * 32 + quad * 8) * E_ + et * 16 + l16;
        bf16x8 c;
#pragma unroll
        for (int j = 0; j < 8; ++j)
            c[j] = (short)bf16rn(src[(size_t)j * E_]);
        h1c[s] = c;
    }
}

// ---------------------------------------------------------------------------
// gemm_pre: 64m x 64u block (grid 32 x 4 x 2 = 256 blocks, 1/CU).
// W-frags (pre-converted by prep) copied global->LDS per K-chunk of 128:
// identity copy, fully coalesced, conflict-free. A-redundancy 4x, W 4x
// (R10-12's prep_gemm had 16x/32x -> ~190 MB fabric traffic = the hidden
// ~30us). Each wave: one 16-row m-tile x 64 u (4 accs), 3-MFMA hi/lo.
//   z==0: keySt4[b][u>>2][j][u&3] = KC*(h1[b,j,:] @ w1[:,u])  (float4-grouped)
//   z==1: qryS  [b][i][u]         = KC*(h2[b,i,:] @ w2[:,u] + b1[u])
// ---------------------------------------------------------------------------
__global__ __launch_bounds__(256) void gemm_pre(
    const float* __restrict__ h1, const float* __restrict__ h2,
    const bf16x8* __restrict__ whi, const bf16x8* __restrict__ wlo,
    const float* __restrict__ b1,
    float* __restrict__ keySt4, float* __restrict__ qryS)
{
    __shared__ bf16x8 WsH[4][4][64];   // [kcl][nt][lane] 16 KB
    __shared__ bf16x8 WsL[4][4][64];   // 16 KB

    const int tid = threadIdx.x;
    const int mb = blockIdx.x;        // m-block of 64 rows (0..31)
    const int ug = blockIdx.y;        // u-group of 64 (0..3)
    const int z  = blockIdx.z;        // which projection
    const int wv = tid >> 6, lane = tid & 63;
    const int quad = lane >> 4, l16 = lane & 15;
    const int m0 = mb * 64 + wv * 16;

    const float* __restrict__ Arow = (z ? h2 : h1) + (size_t)(m0 + l16) * E_;
    const bf16x8* __restrict__ WH = whi + ((size_t)(z * 16 + ug * 4) * 16) * 64;
    const bf16x8* __restrict__ WL = wlo + ((size_t)(z * 16 + ug * 4) * 16) * 64;

    f32x4 acc[4];
#pragma unroll
    for (int i = 0; i < 4; ++i) acc[i] = (f32x4){0.f, 0.f, 0.f, 0.f};

    for (int ch = 0; ch < 4; ++ch) {
        __syncthreads();
        // ---- stage this K-chunk's W frags (identity copy, coalesced) ----
#pragma unroll
        for (int p = 0; p < 4; ++p) {
            const int s = p * 256 + tid;          // 0..1023
            const int nt = s >> 8;
            const int kcl = (s >> 6) & 3;
            const int ln = s & 63;
            const int g = (nt * 16 + ch * 4 + kcl) * 64 + ln;
            WsH[kcl][nt][ln] = WH[g];
            WsL[kcl][nt][ln] = WL[g];
        }
        __syncthreads();
        // ---- MFMA over the chunk ----
#pragma unroll
        for (int kcl = 0; kcl < 4; ++kcl) {
            const int kb = (ch * 4 + kcl) * 32 + quad * 8;
            const float4 x0 = *(const float4*)&Arow[kb];
            const float4 x1 = *(const float4*)&Arow[kb + 4];
            const float xs[8] = {x0.x, x0.y, x0.z, x0.w, x1.x, x1.y, x1.z, x1.w};
            bf16x8 ah, al;
#pragma unroll
            for (int j = 0; j < 8; ++j) {
                short h, l; splitT(xs[j], &h, &l);
                ah[j] = h; al[j] = l;
            }
#pragma unroll
            for (int nt = 0; nt < 4; ++nt) {
                const bf16x8 bh = WsH[kcl][nt][lane];
                const bf16x8 bl = WsL[kcl][nt][lane];
                acc[nt] = __builtin_amdgcn_mfma_f32_16x16x32_bf16(ah, bh, acc[nt], 0, 0, 0);
                acc[nt] = __builtin_amdgcn_mfma_f32_16x16x32_bf16(ah, bl, acc[nt], 0, 0, 0);
                acc[nt] = __builtin_amdgcn_mfma_f32_16x16x32_bf16(al, bh, acc[nt], 0, 0, 0);
            }
        }
    }

    // C/D: row(M=j or i) = quad*4 + r, col(N=u) = l16
    if (z == 0) {
        const int b = m0 >> 9;
        const int j0 = (m0 & (S_ - 1)) + quad * 4;
#pragma unroll
        for (int nt = 0; nt < 4; ++nt) {
            const int u = ug * 64 + nt * 16 + l16;
            float* __restrict__ dst =
                keySt4 + (((size_t)b * 64 + (u >> 2)) * S_ + j0) * 4 + (u & 3);
#pragma unroll
            for (int r = 0; r < 4; ++r)
                dst[r * 4] = acc[nt][r];
        }
    } else {
        const int row = m0 + quad * 4;
#pragma unroll
        for (int nt = 0; nt < 4; ++nt) {
            const int u = ug * 64 + nt * 16 + l16;
            const float bias = KC * b1[u];
#pragma unroll
            for (int r = 0; r < 4; ++r)
                qryS[(size_t)(row + r) * U_ + u] = acc[nt][r] + bias;
        }
    }
}

// ---------------------------------------------------------------------------
// scores + softmax -> P packed in MFMA A-frag order (bf16). R10's exact
// structure (TI=4, 512 thr, grid (128,4), no prefetch) with ONE change: the
// 4 k-values per quadTerm now arrive in a single dwordx4 (keySt4 layout) —
// 4x fewer VMEM issue slots in the hot loop.
// a = sum_u v_u/(exp2(arg)+1); score = c - 2a (c, b2 cancel) ->
// p ~ exp2(-a*KC); |a*KC| <= ~52 so no max-shift needed.
// ---------------------------------------------------------------------------
__device__ __forceinline__ float quadTerm(float a0, float a1, float a2, float a3,
                                          float4 vq, float acc) {
    const float F1 = EXP2F(a0) + 1.f;
    const float F2 = EXP2F(a1) + 1.f;
    const float F3 = EXP2F(a2) + 1.f;
    const float F4 = EXP2F(a3) + 1.f;
    const float P12 = F1 * F2, P34 = F3 * F4;
    const float n12 = fmaf(vq.y, F1, vq.x * F2);
    const float n34 = fmaf(vq.w, F3, vq.z * F4);
    const float num = fmaf(n34, P12, n12 * P34);
    return fmaf(num, RCPF(P12 * P34), acc);
}

__global__ __launch_bounds__(512) void scores_kernel(
    const float* __restrict__ keySt4, const float* __restrict__ qryS,
    const float* __restrict__ v, unsigned short* __restrict__ Pp)
{
    const int i0 = blockIdx.x * 4;
    const int b = blockIdx.y;
    const int t = threadIdx.x;          // j = t
    const int wv = t >> 6;

    __shared__ float ssm[8][4];

    const float4* __restrict__ q0v = (const float4*)(qryS + ((size_t)b * S_ + i0) * U_);
    const float4* __restrict__ q1v = q0v + (U_ / 4);
    const float4* __restrict__ q2v = q0v + 2 * (U_ / 4);
    const float4* __restrict__ q3v = q0v + 3 * (U_ / 4);
    const float4* __restrict__ vv4 = (const float4*)v;
    const float4* __restrict__ kp4 =
        (const float4*)keySt4 + (size_t)b * 64 * S_ + t;   // [b][ub][j]

    float a0 = 0.f, a1 = 0.f, a2 = 0.f, a3 = 0.f;
#pragma unroll 4
    for (int ub = 0; ub < U_ / 4; ++ub) {
        const float4 k4 = kp4[(size_t)ub * S_];        // u = 4ub..4ub+3, col j=t
        const float4 vq = vv4[ub];                     // uniform -> SGPR
        const float4 q0 = q0v[ub], q1 = q1v[ub], q2 = q2v[ub], q3 = q3v[ub];
        a0 = quadTerm(q0.x + k4.x, q0.y + k4.y, q0.z + k4.z, q0.w + k4.w, vq, a0);
        a1 = quadTerm(q1.x + k4.x, q1.y + k4.y, q1.z + k4.z, q1.w + k4.w, vq, a1);
        a2 = quadTerm(q2.x + k4.x, q2.y + k4.y, q2.z + k4.z, q2.w + k4.w, vq, a2);
        a3 = quadTerm(q3.x + k4.x, q3.y + k4.y, q3.z + k4.z, q3.w + k4.w, vq, a3);
    }

    const float p0 = EXP2F(-a0 * KC);
    const float p1 = EXP2F(-a1 * KC);
    const float p2 = EXP2F(-a2 * KC);
    const float p3 = EXP2F(-a3 * KC);
    float s0 = p0, s1 = p1, s2 = p2, s3 = p3;
#pragma unroll
    for (int off = 1; off < 64; off <<= 1) {
        s0 += __shfl_xor(s0, off, 64);
        s1 += __shfl_xor(s1, off, 64);
        s2 += __shfl_xor(s2, off, 64);
        s3 += __shfl_xor(s3, off, 64);
    }
    if ((t & 63) == 0) {
        ssm[wv][0] = s0; ssm[wv][1] = s1; ssm[wv][2] = s2; ssm[wv][3] = s3;
    }
    __syncthreads();
    s0 = ssm[0][0]; s1 = ssm[0][1]; s2 = ssm[0][2]; s3 = ssm[0][3];
#pragma unroll
    for (int k = 1; k < 8; ++k) {
        s0 += ssm[k][0]; s1 += ssm[k][1]; s2 += ssm[k][2]; s3 += ssm[k][3];
    }
    const float r0 = RCPF(s0), r1 = RCPF(s1), r2 = RCPF(s2), r3 = RCPF(s3);

    // pack into A-frag order: slot = (it*16 + j/32)*64 + quad(j)*16 + (i&15),
    // halfword j&7. i0 = 4*blockIdx.x -> rows stay inside one 16-block.
    const int itile = i0 >> 4;
    const int base = (itile * 16 + (t >> 5)) * 64 + (((t >> 3) & 3) << 4);
    unsigned short* __restrict__ pb = Pp + (size_t)b * S_ * S_;
    const int io = i0 & 15, jo = t & 7;
    pb[((base + io + 0) << 3) + jo] = bf16rn(p0 * r0);
    pb[((base + io + 1) << 3) + jo] = bf16rn(p1 * r1);
    pb[((base + io + 2) << 3) + jo] = bf16rn(p2 * r2);
    pb[((base + io + 3) << 3) + jo] = bf16rn(p3 * r3);
}

// ---------------------------------------------------------------------------
// pv (R11 verbatim): out[b] = P[b] @ h1[b]; A-frags pre-packed by scores,
// B-frags (h1c) by prep. Wave-task (b, it, et): one 16i x 16e tile/wave.
// 4096 wave-tasks (grid 1024x256) = 4 waves/SIMD.
// ---------------------------------------------------------------------------
__global__ __launch_bounds__(256) void pv_gemm(
    const unsigned short* __restrict__ Pp, const bf16x8* __restrict__ h1c,
    float* __restrict__ out)
{
    const int tid = threadIdx.x;
    const int wv = tid >> 6, lane = tid & 63;
    const int quad = lane >> 4, l16 = lane & 15;
    const int wt = blockIdx.x * 4 + wv;
    const int b = wt >> 10, rem = wt & 1023;
    const int it = rem >> 5, et = rem & 31;

    const bf16x8* __restrict__ Ab =
        (const bf16x8*)(Pp + (size_t)b * S_ * S_) + (it * 16) * 64 + lane;
    const bf16x8* __restrict__ Bb =
        h1c + ((b * 32 + et) * 16) * 64 + lane;

    f32x4 acc = (f32x4){0.f, 0.f, 0.f, 0.f};

    for (int kc = 0; kc < 16; ++kc) {
        const bf16x8 a8 = Ab[kc * 64];
        const bf16x8 b8 = Bb[kc * 64];
        acc = __builtin_amdgcn_mfma_f32_16x16x32_bf16(a8, b8, acc, 0, 0, 0);
    }

    const int i = it * 16 + quad * 4;
    const int e = et * 16 + l16;
    float* __restrict__ ob = out + ((size_t)b * S_ + i) * E_ + e;
#pragma unroll
    for (int r = 0; r < 4; ++r)
        ob[(size_t)r * E_] = acc[r];
}

extern "C" void kernel_launch(void* const* d_in, const int* in_sizes, int n_in,
                              void* d_out, int out_size, void* d_ws, size_t ws_size,
                              hipStream_t stream) {
    const float* h1 = (const float*)d_in[0];
    const float* h2 = (const float*)d_in[1];
    const float* w  = (const float*)d_in[2];
    const float* b1 = (const float*)d_in[3];
    const float* v  = (const float*)d_in[4];
    // d_in[5] = b2: cancels in softmax, unused.
    float* out = (float*)d_out;

    char* ws = (char*)d_ws;
    float* keySt4 = (float*)ws;                ws += 2u << 20;  // 2 MB
    float* qryS   = (float*)ws;                ws += 2u << 20;  // 2 MB
    unsigned short* Pp = (unsigned short*)ws;  ws += 2u << 20;  // 2 MB
    bf16x8* h1c = (bf16x8*)ws;                 ws += 2u << 20;  // 2 MB
    bf16x8* whi = (bf16x8*)ws;                 ws += 512u << 10; // 512 KB
    bf16x8* wlo = (bf16x8*)ws;                                   // 512 KB

    prep_kernel<<<dim3(640), dim3(256), 0, stream>>>(w, h1, whi, wlo, h1c);
    gemm_pre<<<dim3(32, 4, 2), dim3(256), 0, stream>>>(h1, h2, whi, wlo, b1, keySt4, qryS);
    scores_kernel<<<dim3(S_ / 4, B_), dim3(512), 0, stream>>>(keySt4, qryS, v, Pp);
    pv_gemm<<<dim3(1024), dim3(256), 0, stream>>>(Pp, h1c, out);
}